// Round 1
// baseline (2584.969 us; speedup 1.0000x reference)
//
#include <hip/hip_runtime.h>
#include <math.h>

#define N_ 32
#define C_ 64
#define T_ 300
#define V_ 25
#define H_ 8
#define I_ 16
#define TV_ 7500        // T_*V_
#define CTV_ 480000     // C_*TV_
#define VV_ 625         // V_*V_

// kernel 1 config
#define TC1 10
#define NCH1 30         // T_/TC1
#define TVC1 250        // TC1*V_

// kernel 3 config
#define TC3 4
#define NCH3 75         // T_/TC3
#define TW3 100         // TC3*V_

// ---------------- kernel 1: per-head projections + partial gram ----------------
// grid (N_, NCH1), block 256. Writes partial S into s_part (lives in d_out).
__global__ __launch_bounds__(256) void k1_gram(
    const float* __restrict__ x,
    const float* __restrict__ wa, const float* __restrict__ ba,
    const float* __restrict__ wb, const float* __restrict__ bb,
    float* __restrict__ s_part)
{
    __shared__ float xs[C_][TVC1];   // 64 KB
    __shared__ float as[I_][TVC1];   // 16 KB
    __shared__ float bs[I_][TVC1];   // 16 KB
    const int n = blockIdx.x, ch = blockIdx.y, tid = threadIdx.x;

    // load x chunk: 64 rows x 250 floats (float2: row len 250 is 8B-aligned granular)
    const float* xn = x + n*CTV_ + ch*TVC1;
    for (int idx = tid; idx < C_*125; idx += 256) {
        const int c = idx / 125, q = idx - c*125;
        const float2 v2 = *reinterpret_cast<const float2*>(xn + c*TV_ + 2*q);
        xs[c][2*q]   = v2.x;
        xs[c][2*q+1] = v2.y;
    }

    for (int h = 0; h < H_; ++h) {
        __syncthreads();   // x ready (h=0); as/bs free of prev-head gram reads (h>0)
        // projection: a[i][tv], b[i][tv] for this head
        if (tid < TVC1) {
            const int tv = tid;
            float aacc[I_], bacc[I_];
            #pragma unroll
            for (int i = 0; i < I_; ++i) { aacc[i] = ba[h*I_+i]; bacc[i] = bb[h*I_+i]; }
            const float* wah = wa + h*I_*C_;
            const float* wbh = wb + h*I_*C_;
            for (int c = 0; c < C_; ++c) {
                const float xv = xs[c][tv];        // lane-varying, stride-1 banks
                #pragma unroll
                for (int i = 0; i < I_; ++i) {     // weights lane-uniform -> s_load
                    aacc[i] = fmaf(wah[i*C_+c], xv, aacc[i]);
                    bacc[i] = fmaf(wbh[i*C_+c], xv, bacc[i]);
                }
            }
            #pragma unroll
            for (int i = 0; i < I_; ++i) { as[i][tv] = aacc[i]; bs[i][tv] = bacc[i]; }
        }
        __syncthreads();
        // partial gram: S[v][w] += sum_i sum_tt a[i][tt*25+v]*b[i][tt*25+w]
        for (int idx = tid; idx < VV_; idx += 256) {
            const int v = idx / V_, w = idx - v*V_;
            float s = 0.f;
            #pragma unroll
            for (int i = 0; i < I_; ++i) {
                #pragma unroll
                for (int tt = 0; tt < TC1; ++tt)
                    s = fmaf(as[i][tt*V_+v], bs[i][tt*V_+w], s);
            }
            s_part[((n*NCH1 + ch)*H_ + h)*VV_ + idx] = s;
        }
    }
}

// ---------------- kernel 2: reduce partials, scale, softmax over v, +DepM ------
// grid (H_, N_), block 256.
__global__ __launch_bounds__(256) void k2_softmax(
    const float* __restrict__ s_part, const float* __restrict__ DepM,
    float* __restrict__ A_out)
{
    __shared__ float S[VV_];
    const int h = blockIdx.x, n = blockIdx.y, tid = threadIdx.x;
    for (int j = tid; j < VV_; j += 256) {
        float s = 0.f;
        for (int ch = 0; ch < NCH1; ++ch)
            s += s_part[((n*NCH1 + ch)*H_ + h)*VV_ + j];
        S[j] = s * (1.0f/4800.0f);   // /(INTER*T)
    }
    __syncthreads();
    if (tid < V_) {                   // one thread per column w; softmax over rows v
        const int w = tid;
        float m = -1e30f;
        #pragma unroll
        for (int v = 0; v < V_; ++v) m = fmaxf(m, S[v*V_+w]);
        float e[V_];
        float sum = 0.f;
        #pragma unroll
        for (int v = 0; v < V_; ++v) { e[v] = expf(S[v*V_+w] - m); sum += e[v]; }
        const float inv = 1.0f / sum;
        #pragma unroll
        for (int v = 0; v < V_; ++v)
            A_out[(h*N_ + n)*VV_ + v*V_ + w] = e[v]*inv + DepM[h*VV_ + v*V_ + w];
    }
}

// ---------------- kernel 3: fused z = x@A_h ; y += wd_h @ z ; BN partials ------
// grid (N_, NCH3), block 256, 2 blocks/CU (70.3 KB LDS).
__global__ __launch_bounds__(256, 2) void k3_main(
    const float* __restrict__ x, const float* __restrict__ A_ws,
    const float* __restrict__ wd, const float* __restrict__ bd,
    float* __restrict__ y_out, float* __restrict__ bn_acc)
{
    __shared__ float xs[C_][TW3];     // 25.6 KB
    __shared__ float zs[C_][TW3];     // 25.6 KB (reused as y staging at end)
    __shared__ float As[VV_];         // 2.5 KB
    __shared__ float wds[C_*65];      // 16.64 KB, padded stride 65 (bank-conflict-free)
    const int n = blockIdx.x, tc = blockIdx.y, tid = threadIdx.x;

    const float* xn = x + n*CTV_ + tc*TW3;
    for (int idx = tid; idx < C_*25; idx += 256) {   // float4 loads, 100 floats/row
        const int c = idx / 25, q = idx - c*25;
        *reinterpret_cast<float4*>(&xs[c][4*q]) =
            *reinterpret_cast<const float4*>(xn + c*TV_ + 4*q);
    }

    // z-step roles: thread (c, wq) owns 4t x (7 or 4) w
    const int zc = tid >> 2, zwq = tid & 3;
    const int znw = (zwq < 3) ? 7 : 4;
    // y-step roles: thread (og, jj, ks) owns o=4og..4og+3, e = e0+16*kk
    const int og = tid >> 4, jj = (tid >> 2) & 3, ks = tid & 3;
    const int e0 = jj + 4*ks;                 // 0..15, bijective over 16-lane group
    const int nkk = (e0 <= 3) ? 7 : 6;        // e < 100

    float yacc[4][7];
    #pragma unroll
    for (int oo = 0; oo < 4; ++oo)
        #pragma unroll
        for (int k = 0; k < 7; ++k) yacc[oo][k] = 0.f;

    for (int h = 0; h < H_; ++h) {
        __syncthreads();   // xs ready (h=0); zs/wds/As free of prev-head reads
        for (int idx = tid; idx < VV_; idx += 256)
            As[idx] = A_ws[(h*N_ + n)*VV_ + idx];
        for (int idx = tid; idx < C_*C_; idx += 256)
            wds[(idx >> 6)*65 + (idx & 63)] = wd[h*C_*C_ + idx];
        __syncthreads();

        // z[c][t*25+w] = sum_v xs[c][t*25+v] * A[v*25+w]
        {
            float zacc[4][7];
            #pragma unroll
            for (int t = 0; t < 4; ++t)
                #pragma unroll
                for (int ww = 0; ww < 7; ++ww) zacc[t][ww] = 0.f;
            for (int v = 0; v < V_; ++v) {
                float xr[4];
                #pragma unroll
                for (int t = 0; t < 4; ++t) xr[t] = xs[zc][t*V_ + v];
                #pragma unroll
                for (int ww = 0; ww < 7; ++ww) {
                    if (ww < znw) {
                        const float ar = As[v*V_ + zwq*7 + ww];
                        #pragma unroll
                        for (int t = 0; t < 4; ++t)
                            zacc[t][ww] = fmaf(xr[t], ar, zacc[t][ww]);
                    }
                }
            }
            #pragma unroll
            for (int t = 0; t < 4; ++t)
                #pragma unroll
                for (int ww = 0; ww < 7; ++ww)
                    if (ww < znw) zs[zc][t*V_ + zwq*7 + ww] = zacc[t][ww];
        }
        __syncthreads();

        // y[o][e] += sum_c wds[o][c] * z[c][e]
        for (int c = 0; c < C_; ++c) {
            float wr[4];
            #pragma unroll
            for (int oo = 0; oo < 4; ++oo) wr[oo] = wds[(og*4 + oo)*65 + c];
            #pragma unroll
            for (int kk = 0; kk < 7; ++kk) {
                if (kk < nkk) {
                    const float zr = zs[c][e0 + 16*kk];
                    #pragma unroll
                    for (int oo = 0; oo < 4; ++oo)
                        yacc[oo][kk] = fmaf(wr[oo], zr, yacc[oo][kk]);
                }
            }
        }
    }

    // + sum_h bd[h,o]
    #pragma unroll
    for (int oo = 0; oo < 4; ++oo) {
        float bias = 0.f;
        #pragma unroll
        for (int h = 0; h < H_; ++h) bias += bd[h*C_ + og*4 + oo];
        #pragma unroll
        for (int kk = 0; kk < 7; ++kk) if (kk < nkk) yacc[oo][kk] += bias;
    }

    // BN partial sums: reduce over 16-lane group (same og), 128 atomics/block
    #pragma unroll
    for (int oo = 0; oo < 4; ++oo) {
        float s1 = 0.f, s2 = 0.f;
        #pragma unroll
        for (int kk = 0; kk < 7; ++kk)
            if (kk < nkk) { const float yv = yacc[oo][kk]; s1 += yv; s2 += yv*yv; }
        #pragma unroll
        for (int off = 1; off < 16; off <<= 1) {
            s1 += __shfl_xor(s1, off, 64);
            s2 += __shfl_xor(s2, off, 64);
        }
        if ((tid & 15) == 0) {
            atomicAdd(&bn_acc[og*4 + oo], s1);
            atomicAdd(&bn_acc[64 + og*4 + oo], s2);
        }
    }

    // stage y into zs, then coalesced float4 store
    __syncthreads();
    #pragma unroll
    for (int oo = 0; oo < 4; ++oo)
        #pragma unroll
        for (int kk = 0; kk < 7; ++kk)
            if (kk < nkk) zs[og*4 + oo][e0 + 16*kk] = yacc[oo][kk];
    __syncthreads();
    float* yout = y_out + n*CTV_ + tc*TW3;
    for (int idx = tid; idx < C_*25; idx += 256) {
        const int o = idx / 25, q = idx - o*25;
        *reinterpret_cast<float4*>(yout + o*TV_ + 4*q) =
            *reinterpret_cast<const float4*>(&zs[o][4*q]);
    }
}

// ---------------- kernel 4: BN normalize + residual + relu (in-place on y) -----
__global__ __launch_bounds__(256) void k4_bn(
    float* yio, const float* __restrict__ x, const float* __restrict__ bn_acc,
    const float* __restrict__ gamma, const float* __restrict__ beta)
{
    const int idx = blockIdx.x*256 + threadIdx.x;   // float4 index, exactly 3,840,000
    const int c = (idx / 1875) & 63;                // 1875 float4 per (n,c) plane
    const float invM = 1.0f / 240000.0f;            // N*T*V
    const float mean = bn_acc[c] * invM;
    const float var  = bn_acc[64 + c] * invM - mean*mean;
    const float scale = gamma[c] * rsqrtf(var + 1e-5f);
    const float shift = beta[c] - mean*scale;
    const float4 y4 = reinterpret_cast<const float4*>(yio)[idx];
    const float4 x4 = reinterpret_cast<const float4*>(x)[idx];
    float4 r;
    r.x = fmaxf(0.f, fmaf(y4.x, scale, shift) + x4.x);
    r.y = fmaxf(0.f, fmaf(y4.y, scale, shift) + x4.y);
    r.z = fmaxf(0.f, fmaf(y4.z, scale, shift) + x4.z);
    r.w = fmaxf(0.f, fmaf(y4.w, scale, shift) + x4.w);
    reinterpret_cast<float4*>(yio)[idx] = r;
}

extern "C" void kernel_launch(void* const* d_in, const int* in_sizes, int n_in,
                              void* d_out, int out_size, void* d_ws, size_t ws_size,
                              hipStream_t stream) {
    const float* x     = (const float*)d_in[0];
    const float* DepM  = (const float*)d_in[1];
    const float* wa    = (const float*)d_in[2];
    const float* ba    = (const float*)d_in[3];
    const float* wb    = (const float*)d_in[4];
    const float* bb    = (const float*)d_in[5];
    const float* wd    = (const float*)d_in[6];
    const float* bd    = (const float*)d_in[7];
    const float* gamma = (const float*)d_in[8];
    const float* beta  = (const float*)d_in[9];
    float* out = (float*)d_out;

    // ws layout: A (160000 floats) + bn_acc (128 floats)  -> needs ~641 KB
    float* A_ws   = (float*)d_ws;
    float* bn_acc = (float*)d_ws + 160000;
    // gram partials use d_out as scratch (19.2 MB < 61.4 MB); y overwrites later
    float* s_part = out;

    k1_gram<<<dim3(N_, NCH1), dim3(256), 0, stream>>>(x, wa, ba, wb, bb, s_part);
    k2_softmax<<<dim3(H_, N_), dim3(256), 0, stream>>>(s_part, DepM, A_ws);
    hipMemsetAsync(bn_acc, 0, 128*sizeof(float), stream);
    k3_main<<<dim3(N_, NCH3), dim3(256), 0, stream>>>(x, A_ws, wd, bd, out, bn_acc);
    k4_bn<<<dim3(15000), dim3(256), 0, stream>>>(out, x, bn_acc, gamma, beta);
}

// Round 3
// 871.459 us; speedup vs baseline: 2.9663x; 2.9663x over previous
//
#include <hip/hip_runtime.h>
#include <math.h>

#define N_ 32
#define C_ 64
#define T_ 300
#define V_ 25
#define H_ 8
#define I_ 16
#define TV_ 7500        // T_*V_
#define CTV_ 480000     // C_*TV_
#define VV_ 625         // V_*V_

// kernel 1 config
#define TC1 10
#define NCH1 30         // T_/TC1
#define TVC1 250        // TC1*V_

// kernel 3 (MFMA) config: 5 timesteps/block -> TW=125 (t,v) columns
#define NCK 60          // T_/5

typedef __attribute__((ext_vector_type(8))) short bf16x8;
typedef __attribute__((ext_vector_type(4))) float f32x4;

__device__ inline f32x4 mfma16(bf16x8 a, bf16x8 b, f32x4 c) {
    return __builtin_amdgcn_mfma_f32_16x16x32_bf16(a, b, c, 0, 0, 0);
}

__device__ inline unsigned short f2bf(float f) {
    union { float f; unsigned u; } v; v.f = f;
    const unsigned r = v.u + 0x7FFFu + ((v.u >> 16) & 1u);   // round-to-nearest-even
    return (unsigned short)(r >> 16);
}
__device__ inline bf16x8 pack8(float4 a, float4 b) {
    bf16x8 r;
    r[0] = (short)f2bf(a.x); r[1] = (short)f2bf(a.y);
    r[2] = (short)f2bf(a.z); r[3] = (short)f2bf(a.w);
    r[4] = (short)f2bf(b.x); r[5] = (short)f2bf(b.y);
    r[6] = (short)f2bf(b.z); r[7] = (short)f2bf(b.w);
    return r;
}

// ---------------- kernel 1: per-head projections + partial gram (unchanged) ----
__global__ __launch_bounds__(256) void k1_gram(
    const float* __restrict__ x,
    const float* __restrict__ wa, const float* __restrict__ ba,
    const float* __restrict__ wb, const float* __restrict__ bb,
    float* __restrict__ s_part)
{
    __shared__ float xs[C_][TVC1];
    __shared__ float as[I_][TVC1];
    __shared__ float bs[I_][TVC1];
    const int n = blockIdx.x, ch = blockIdx.y, tid = threadIdx.x;

    const float* xn = x + n*CTV_ + ch*TVC1;
    for (int idx = tid; idx < C_*125; idx += 256) {
        const int c = idx / 125, q = idx - c*125;
        const float2 v2 = *reinterpret_cast<const float2*>(xn + c*TV_ + 2*q);
        xs[c][2*q]   = v2.x;
        xs[c][2*q+1] = v2.y;
    }

    for (int h = 0; h < H_; ++h) {
        __syncthreads();
        if (tid < TVC1) {
            const int tv = tid;
            float aacc[I_], bacc[I_];
            #pragma unroll
            for (int i = 0; i < I_; ++i) { aacc[i] = ba[h*I_+i]; bacc[i] = bb[h*I_+i]; }
            const float* wah = wa + h*I_*C_;
            const float* wbh = wb + h*I_*C_;
            for (int c = 0; c < C_; ++c) {
                const float xv = xs[c][tv];
                #pragma unroll
                for (int i = 0; i < I_; ++i) {
                    aacc[i] = fmaf(wah[i*C_+c], xv, aacc[i]);
                    bacc[i] = fmaf(wbh[i*C_+c], xv, bacc[i]);
                }
            }
            #pragma unroll
            for (int i = 0; i < I_; ++i) { as[i][tv] = aacc[i]; bs[i][tv] = bacc[i]; }
        }
        __syncthreads();
        for (int idx = tid; idx < VV_; idx += 256) {
            const int v = idx / V_, w = idx - v*V_;
            float s = 0.f;
            #pragma unroll
            for (int i = 0; i < I_; ++i) {
                #pragma unroll
                for (int tt = 0; tt < TC1; ++tt)
                    s = fmaf(as[i][tt*V_+v], bs[i][tt*V_+w], s);
            }
            s_part[((n*NCH1 + ch)*H_ + h)*VV_ + idx] = s;
        }
    }
}

// ---------------- kernel 2: reduce partials, scale, softmax over v, +DepM ------
__global__ __launch_bounds__(256) void k2_softmax(
    const float* __restrict__ s_part, const float* __restrict__ DepM,
    float* __restrict__ A_out)
{
    __shared__ float S[VV_];
    const int h = blockIdx.x, n = blockIdx.y, tid = threadIdx.x;
    for (int j = tid; j < VV_; j += 256) {
        float s = 0.f;
        for (int ch = 0; ch < NCH1; ++ch)
            s += s_part[((n*NCH1 + ch)*H_ + h)*VV_ + j];
        S[j] = s * (1.0f/4800.0f);
    }
    __syncthreads();
    if (tid < V_) {
        const int w = tid;
        float m = -1e30f;
        #pragma unroll
        for (int v = 0; v < V_; ++v) m = fmaxf(m, S[v*V_+w]);
        float e[V_];
        float sum = 0.f;
        #pragma unroll
        for (int v = 0; v < V_; ++v) { e[v] = expf(S[v*V_+w] - m); sum += e[v]; }
        const float inv = 1.0f / sum;
        #pragma unroll
        for (int v = 0; v < V_; ++v)
            A_out[(h*N_ + n)*VV_ + v*V_ + w] = e[v]*inv + DepM[h*VV_ + v*V_ + w];
    }
}

// ---------------- kernel 3: MFMA bf16 fused z = x@A_h ; y += wd_h@z ------------
// Per block: n = blockIdx.x, 5-timestep chunk ck = blockIdx.y. 4 waves.
// xa: x as step-A A-frags, rows r=t*64+c, v padded to 40 (16B-aligned frag reads)
// zt: z transposed [tw][c] for step-B B-frags, c padded to 72
// y accumulates in registers (8 f32x4 per lane) across all 8 heads.
__global__ __launch_bounds__(256, 3) void k3_mfma(
    const float* __restrict__ x, const float* __restrict__ A_ws,
    const float* __restrict__ wd, const float* __restrict__ bd,
    float* __restrict__ y_out, float* __restrict__ bnS)
{
    __shared__ __align__(16) unsigned short xa[320*40];   // 25.6 KB
    __shared__ __align__(16) unsigned short zt[128*72];   // 18.4 KB
    __shared__ __align__(16) unsigned short At[32*40];    // 2.56 KB
    const int n = blockIdx.x, ck = blockIdx.y, tid = threadIdx.x;
    const int lane = tid & 63, wave = tid >> 6;
    const int l15 = lane & 15, lhi = lane >> 4;
    const int obase = wave * 16;
    const f32x4 zero4 = {0.f, 0.f, 0.f, 0.f};

    // ---- stage x (fp32 global -> bf16 LDS), once for all heads ----
    const float* xblk = x + n*CTV_ + ck*125;
    for (int idx = tid; idx < 8000; idx += 256) {
        const int c = idx / 125, tv = idx - c*125;
        const int t = tv / 25, v = tv - t*25;
        xa[(t*64 + c)*40 + v] = f2bf(xblk[c*TV_ + tv]);
    }
    for (int idx = tid; idx < 320*7; idx += 256) {        // zero v-pad 25..31 (k-range read by MFMA)
        const int r = idx / 7, v = 25 + (idx - r*7);
        xa[r*40 + v] = 0;
    }

    f32x4 yacc[8];
    #pragma unroll
    for (int i = 0; i < 8; ++i) yacc[i] = zero4;

    for (int h = 0; h < H_; ++h) {
        __syncthreads();   // xa ready (h=0); zt reads of prev head complete (h>0)
        // At[w][v] = A_h[v][w] (transposed, zero-padded to 32x32)
        const float* Ah = A_ws + (h*N_ + n)*VV_;
        for (int e = tid; e < 32*32; e += 256) {
            const int w = e >> 5, v = e & 31;
            At[w*40 + v] = (w < 25 && v < 25) ? f2bf(Ah[v*25 + w]) : (unsigned short)0;
        }
        // wd A-frags for step B, straight from global (row o = obase+l15, k = c)
        const float* wp = wd + h*4096 + (obase + l15)*64 + lhi*8;
        const float4 f0 = *(const float4*)(wp);
        const float4 f1 = *(const float4*)(wp + 4);
        const float4 g0 = *(const float4*)(wp + 32);
        const float4 g1 = *(const float4*)(wp + 36);
        const bf16x8 wa0 = pack8(f0, f1);
        const bf16x8 wa1 = pack8(g0, g1);
        __syncthreads();   // At ready

        // ---- step A: z[(t,c)][w] = sum_v x * A  (20 m-tiles, 2 n-tiles, K=32) ----
        const bf16x8 bA0 = *(const bf16x8*)&At[l15*40 + lhi*8];          // w 0..15
        const bf16x8 bA1 = *(const bf16x8*)&At[(16 + l15)*40 + lhi*8];   // w 16..31
        #pragma unroll
        for (int mi = 0; mi < 5; ++mi) {
            const int m = wave + mi*4;                    // m-tile 0..19
            const int r = m*16 + l15;                     // row = t*64 + c
            const bf16x8 af = *(const bf16x8*)&xa[r*40 + lhi*8];
            const f32x4 d0 = mfma16(af, bA0, zero4);
            const f32x4 d1 = mfma16(af, bA1, zero4);
            const int t = m >> 2, c0 = (m & 3)*16 + lhi*4;
            uint2 p0;
            p0.x = (unsigned)f2bf(d0[0]) | ((unsigned)f2bf(d0[1]) << 16);
            p0.y = (unsigned)f2bf(d0[2]) | ((unsigned)f2bf(d0[3]) << 16);
            *(uint2*)&zt[(t*25 + l15)*72 + c0] = p0;      // cols w=0..15
            if (l15 < 9) {                                // cols w=16..24 only
                uint2 p1;
                p1.x = (unsigned)f2bf(d1[0]) | ((unsigned)f2bf(d1[1]) << 16);
                p1.y = (unsigned)f2bf(d1[2]) | ((unsigned)f2bf(d1[3]) << 16);
                *(uint2*)&zt[(t*25 + 16 + l15)*72 + c0] = p1;
            }
        }
        __syncthreads();   // zt ready

        // ---- step B: y[o][tw] += wd_h @ z  (1 m-tile/wave, 8 n-tiles, K=64) ----
        #pragma unroll
        for (int nt = 0; nt < 8; ++nt) {
            const int tw = nt*16 + l15;
            const bf16x8 b0 = *(const bf16x8*)&zt[tw*72 + lhi*8];        // c 0..31
            const bf16x8 b1 = *(const bf16x8*)&zt[tw*72 + 32 + lhi*8];   // c 32..63
            yacc[nt] = mfma16(wa0, b0, yacc[nt]);
            yacc[nt] = mfma16(wa1, b1, yacc[nt]);
        }
    }

    // ---- epilogue: bias, BN partials, store ----
    float bsum[4];
    #pragma unroll
    for (int rg = 0; rg < 4; ++rg) {
        const int o = obase + lhi*4 + rg;
        float s = 0.f;
        #pragma unroll
        for (int h = 0; h < H_; ++h) s += bd[h*64 + o];
        bsum[rg] = s;
    }
    float s1[4] = {0,0,0,0}, s2[4] = {0,0,0,0};
    #pragma unroll
    for (int nt = 0; nt < 8; ++nt) {
        const int tw = nt*16 + l15;
        if (tw < 125) {
            #pragma unroll
            for (int rg = 0; rg < 4; ++rg) {
                const float v = yacc[nt][rg] + bsum[rg];
                yacc[nt][rg] = v;
                s1[rg] += v;
                s2[rg] += v*v;
            }
        }
    }
    #pragma unroll
    for (int rg = 0; rg < 4; ++rg) {
        #pragma unroll
        for (int off = 1; off < 16; off <<= 1) {
            s1[rg] += __shfl_xor(s1[rg], off, 64);
            s2[rg] += __shfl_xor(s2[rg], off, 64);
        }
    }
    if (l15 == 0) {   // 4 lanes/wave, each owns channels obase+lhi*4+0..3
        const int slot = (n*NCK + ck) & 31;               // 32-way spread: no hot lines
        #pragma unroll
        for (int rg = 0; rg < 4; ++rg) {
            const int o = obase + lhi*4 + rg;
            atomicAdd(&bnS[o*32 + slot], s1[rg]);
            atomicAdd(&bnS[2048 + o*32 + slot], s2[rg]);
        }
    }
    float* yo = y_out + n*CTV_ + ck*125;
    #pragma unroll
    for (int nt = 0; nt < 8; ++nt) {
        const int tw = nt*16 + l15;
        if (tw < 125) {
            #pragma unroll
            for (int rg = 0; rg < 4; ++rg) {
                const int o = obase + lhi*4 + rg;
                yo[o*TV_ + tw] = yacc[nt][rg];
            }
        }
    }
}

// ---------------- kernel 3r: fold 32-way-spread BN partials -> bn_acc[128] -----
__global__ void k3_reduce(const float* __restrict__ bnS, float* __restrict__ bn_acc)
{
    const int tid = threadIdx.x;
    if (tid < 128) {
        float s = 0.f;
        #pragma unroll
        for (int i = 0; i < 32; ++i) s += bnS[tid*32 + i];
        bn_acc[tid] = s;
    }
}

// ---------------- kernel 4: BN normalize + residual + relu (unchanged) ---------
__global__ __launch_bounds__(256) void k4_bn(
    float* yio, const float* __restrict__ x, const float* __restrict__ bn_acc,
    const float* __restrict__ gamma, const float* __restrict__ beta)
{
    const int idx = blockIdx.x*256 + threadIdx.x;
    const int c = (idx / 1875) & 63;
    const float invM = 1.0f / 240000.0f;
    const float mean = bn_acc[c] * invM;
    const float var  = bn_acc[64 + c] * invM - mean*mean;
    const float scale = gamma[c] * rsqrtf(var + 1e-5f);
    const float shift = beta[c] - mean*scale;
    const float4 y4 = reinterpret_cast<const float4*>(yio)[idx];
    const float4 x4 = reinterpret_cast<const float4*>(x)[idx];
    float4 r;
    r.x = fmaxf(0.f, fmaf(y4.x, scale, shift) + x4.x);
    r.y = fmaxf(0.f, fmaf(y4.y, scale, shift) + x4.y);
    r.z = fmaxf(0.f, fmaf(y4.z, scale, shift) + x4.z);
    r.w = fmaxf(0.f, fmaf(y4.w, scale, shift) + x4.w);
    reinterpret_cast<float4*>(yio)[idx] = r;
}

extern "C" void kernel_launch(void* const* d_in, const int* in_sizes, int n_in,
                              void* d_out, int out_size, void* d_ws, size_t ws_size,
                              hipStream_t stream) {
    const float* x     = (const float*)d_in[0];
    const float* DepM  = (const float*)d_in[1];
    const float* wa    = (const float*)d_in[2];
    const float* ba    = (const float*)d_in[3];
    const float* wb    = (const float*)d_in[4];
    const float* bb    = (const float*)d_in[5];
    const float* wd    = (const float*)d_in[6];
    const float* bd    = (const float*)d_in[7];
    const float* gamma = (const float*)d_in[8];
    const float* beta  = (const float*)d_in[9];
    float* out = (float*)d_out;

    // ws: A (160000 f) | bnS spread partials (4096 f) | bn_acc (128 f)  ~657 KB
    float* A_ws   = (float*)d_ws;
    float* bnS    = (float*)d_ws + 160000;
    float* bn_acc = (float*)d_ws + 164096;
    float* s_part = out;   // gram partials use d_out as scratch before y overwrites

    k1_gram<<<dim3(N_, NCH1), dim3(256), 0, stream>>>(x, wa, ba, wb, bb, s_part);
    k2_softmax<<<dim3(H_, N_), dim3(256), 0, stream>>>(s_part, DepM, A_ws);
    (void)hipMemsetAsync(bnS, 0, 4096*sizeof(float), stream);
    k3_mfma<<<dim3(N_, NCK), dim3(256), 0, stream>>>(x, A_ws, wd, bd, out, bnS);
    k3_reduce<<<dim3(1), dim3(128), 0, stream>>>(bnS, bn_acc);
    k4_bn<<<dim3(15000), dim3(256), 0, stream>>>(out, x, bn_acc, gamma, beta);
}

// Round 4
// 288.656 us; speedup vs baseline: 8.9552x; 3.0190x over previous
//
#include <hip/hip_runtime.h>
#include <math.h>

#define N_ 32
#define C_ 64
#define T_ 300
#define V_ 25
#define H_ 8
#define I_ 16
#define TV_ 7500        // T_*V_
#define CTV_ 480000     // C_*TV_
#define VV_ 625         // V_*V_

// kernel 1 config: 10 timesteps/chunk -> 250 tv columns, gram K = 160
#define TC1 10
#define NCH1 30         // T_/TC1
#define TVC1 250        // TC1*V_

// kernel 3 (MFMA) config: 5 timesteps/block -> TW=125 (t,v) columns
#define NCK 60          // T_/5

typedef __attribute__((ext_vector_type(8))) short bf16x8;
typedef __attribute__((ext_vector_type(4))) float f32x4;

__device__ inline f32x4 mfma16(bf16x8 a, bf16x8 b, f32x4 c) {
    return __builtin_amdgcn_mfma_f32_16x16x32_bf16(a, b, c, 0, 0, 0);
}

__device__ inline unsigned short f2bf(float f) {
    union { float f; unsigned u; } v; v.f = f;
    const unsigned r = v.u + 0x7FFFu + ((v.u >> 16) & 1u);   // round-to-nearest-even
    return (unsigned short)(r >> 16);
}
__device__ inline bf16x8 pack8(float4 a, float4 b) {
    bf16x8 r;
    r[0] = (short)f2bf(a.x); r[1] = (short)f2bf(a.y);
    r[2] = (short)f2bf(a.z); r[3] = (short)f2bf(a.w);
    r[4] = (short)f2bf(b.x); r[5] = (short)f2bf(b.y);
    r[6] = (short)f2bf(b.z); r[7] = (short)f2bf(b.w);
    return r;
}

// ---------------- kernel 1 (NEW): MFMA projections + partial gram --------------
// Per block: n, chunk ch of 10 timesteps. 4 waves, 2 blocks/CU (57 KB LDS).
// xt[tv][c]: x transposed, bf16, pad 72 (16B-aligned rows)
// at[v][kk], bt[w][kk]: projection outputs in gram-operand layout, kk=t*16+i
__global__ __launch_bounds__(256, 2) void k1_mfma(
    const float* __restrict__ x,
    const float* __restrict__ wa, const float* __restrict__ ba,
    const float* __restrict__ wb, const float* __restrict__ bb,
    float* __restrict__ s_part)
{
    __shared__ __align__(16) unsigned short xt[256*72];   // 36.9 KB
    __shared__ __align__(16) unsigned short at[32*168];   // 10.75 KB
    __shared__ __align__(16) unsigned short bt[32*168];   // 10.75 KB
    const int n = blockIdx.x, ch = blockIdx.y, tid = threadIdx.x;
    const int lane = tid & 63, wave = tid >> 6;
    const int l15 = lane & 15, lhi = lane >> 4;
    const f32x4 zero4 = {0.f, 0.f, 0.f, 0.f};

    // ---- stage xt: coalesced global reads (64 consecutive tv per cg), b64 LDS writes
    const float* xblk = x + n*CTV_ + ch*TVC1;
    for (int idx = tid; idx < 4000; idx += 256) {
        const int cg = idx / 250, tv = idx - cg*250;
        const float p0 = xblk[(cg*4+0)*TV_ + tv];
        const float p1 = xblk[(cg*4+1)*TV_ + tv];
        const float p2 = xblk[(cg*4+2)*TV_ + tv];
        const float p3 = xblk[(cg*4+3)*TV_ + tv];
        uint2 q;
        q.x = (unsigned)f2bf(p0) | ((unsigned)f2bf(p1) << 16);
        q.y = (unsigned)f2bf(p2) | ((unsigned)f2bf(p3) << 16);
        *(uint2*)&xt[tv*72 + cg*4] = q;
    }

    for (int h = 0; h < H_; ++h) {
        // wa/wb A-frags (row i=l15, k=c) + bias C-operand, straight from global (L2-hot)
        const float* wap = wa + h*1024 + l15*64 + lhi*8;
        const float* wbp = wb + h*1024 + l15*64 + lhi*8;
        const bf16x8 waf0 = pack8(*(const float4*)(wap),    *(const float4*)(wap+4));
        const bf16x8 waf1 = pack8(*(const float4*)(wap+32), *(const float4*)(wap+36));
        const bf16x8 wbf0 = pack8(*(const float4*)(wbp),    *(const float4*)(wbp+4));
        const bf16x8 wbf1 = pack8(*(const float4*)(wbp+32), *(const float4*)(wbp+36));
        const float4 bav = *(const float4*)&ba[h*16 + lhi*4];
        const float4 bbv = *(const float4*)&bb[h*16 + lhi*4];
        f32x4 ca; ca[0]=bav.x; ca[1]=bav.y; ca[2]=bav.z; ca[3]=bav.w;
        f32x4 cb; cb[0]=bbv.x; cb[1]=bbv.y; cb[2]=bbv.z; cb[3]=bbv.w;

        __syncthreads();   // h=0: xt staged; h>0: prev gram LDS-reads done

        // ---- projection: D[i][tv] = wa/wb @ x, 16 n-tiles, K=64 (2 steps) ----
        #pragma unroll
        for (int w2 = 0; w2 < 4; ++w2) {
            const int nt = wave*4 + w2;            // n-tile 0..15
            const int tv = nt*16 + l15;            // tv column (250..255 garbage)
            const bf16x8 xb0 = *(const bf16x8*)&xt[tv*72 + lhi*8];        // c 0..31
            const bf16x8 xb1 = *(const bf16x8*)&xt[tv*72 + 32 + lhi*8];   // c 32..63
            f32x4 da = mfma16(waf0, xb0, ca);
            da = mfma16(waf1, xb1, da);
            f32x4 db = mfma16(wbf0, xb0, cb);
            db = mfma16(wbf1, xb1, db);
            if (tv < TVC1) {
                const int t = (tv*41) >> 10, v = tv - t*25;   // tv/25, tv%25
                uint2 pa, pb;
                pa.x = (unsigned)f2bf(da[0]) | ((unsigned)f2bf(da[1]) << 16);
                pa.y = (unsigned)f2bf(da[2]) | ((unsigned)f2bf(da[3]) << 16);
                pb.x = (unsigned)f2bf(db[0]) | ((unsigned)f2bf(db[1]) << 16);
                pb.y = (unsigned)f2bf(db[2]) | ((unsigned)f2bf(db[3]) << 16);
                *(uint2*)&at[v*168 + t*16 + lhi*4] = pa;   // rows i=lhi*4+0..3 contig
                *(uint2*)&bt[v*168 + t*16 + lhi*4] = pb;
            }
        }
        __syncthreads();   // at/bt ready

        // ---- gram: S[v][w] += a^T b over kk=160; wave -> 16x16 quadrant ----
        const int mq = wave >> 1, nq = wave & 1;
        f32x4 acc = zero4;
        #pragma unroll
        for (int ks = 0; ks < 5; ++ks) {
            const bf16x8 aA = *(const bf16x8*)&at[(mq*16 + l15)*168 + ks*32 + lhi*8];
            const bf16x8 bB = *(const bf16x8*)&bt[(nq*16 + l15)*168 + ks*32 + lhi*8];
            acc = mfma16(aA, bB, acc);
        }
        const int w = nq*16 + l15;
        float* sp = s_part + ((n*NCH1 + ch)*H_ + h)*VV_;
        if (w < V_) {
            #pragma unroll
            for (int rg = 0; rg < 4; ++rg) {
                const int v = mq*16 + lhi*4 + rg;
                if (v < V_) sp[v*V_ + w] = acc[rg];
            }
        }
    }
}

// ---------------- kernel 2: reduce partials, scale, softmax over v, +DepM ------
__global__ __launch_bounds__(256) void k2_softmax(
    const float* __restrict__ s_part, const float* __restrict__ DepM,
    float* __restrict__ A_out)
{
    __shared__ float S[VV_];
    const int h = blockIdx.x, n = blockIdx.y, tid = threadIdx.x;
    for (int j = tid; j < VV_; j += 256) {
        float s = 0.f;
        for (int ch = 0; ch < NCH1; ++ch)
            s += s_part[((n*NCH1 + ch)*H_ + h)*VV_ + j];
        S[j] = s * (1.0f/4800.0f);
    }
    __syncthreads();
    if (tid < V_) {
        const int w = tid;
        float m = -1e30f;
        #pragma unroll
        for (int v = 0; v < V_; ++v) m = fmaxf(m, S[v*V_+w]);
        float e[V_];
        float sum = 0.f;
        #pragma unroll
        for (int v = 0; v < V_; ++v) { e[v] = expf(S[v*V_+w] - m); sum += e[v]; }
        const float inv = 1.0f / sum;
        #pragma unroll
        for (int v = 0; v < V_; ++v)
            A_out[(h*N_ + n)*VV_ + v*V_ + w] = e[v]*inv + DepM[h*VV_ + v*V_ + w];
    }
}

// ---------------- kernel 3: MFMA bf16 fused z = x@A_h ; y += wd_h@z ------------
__global__ __launch_bounds__(256, 3) void k3_mfma(
    const float* __restrict__ x, const float* __restrict__ A_ws,
    const float* __restrict__ wd, const float* __restrict__ bd,
    float* __restrict__ y_out, float* __restrict__ bnS)
{
    __shared__ __align__(16) unsigned short xa[320*40];   // 25.6 KB
    __shared__ __align__(16) unsigned short zt[128*72];   // 18.4 KB
    __shared__ __align__(16) unsigned short At[32*40];    // 2.56 KB
    const int n = blockIdx.x, ck = blockIdx.y, tid = threadIdx.x;
    const int lane = tid & 63, wave = tid >> 6;
    const int l15 = lane & 15, lhi = lane >> 4;
    const int obase = wave * 16;
    const f32x4 zero4 = {0.f, 0.f, 0.f, 0.f};

    const float* xblk = x + n*CTV_ + ck*125;
    for (int idx = tid; idx < 8000; idx += 256) {
        const int c = idx / 125, tv = idx - c*125;
        const int t = tv / 25, v = tv - t*25;
        xa[(t*64 + c)*40 + v] = f2bf(xblk[c*TV_ + tv]);
    }
    for (int idx = tid; idx < 320*7; idx += 256) {
        const int r = idx / 7, v = 25 + (idx - r*7);
        xa[r*40 + v] = 0;
    }

    f32x4 yacc[8];
    #pragma unroll
    for (int i = 0; i < 8; ++i) yacc[i] = zero4;

    for (int h = 0; h < H_; ++h) {
        __syncthreads();
        const float* Ah = A_ws + (h*N_ + n)*VV_;
        for (int e = tid; e < 32*32; e += 256) {
            const int w = e >> 5, v = e & 31;
            At[w*40 + v] = (w < 25 && v < 25) ? f2bf(Ah[v*25 + w]) : (unsigned short)0;
        }
        const float* wp = wd + h*4096 + (obase + l15)*64 + lhi*8;
        const float4 f0 = *(const float4*)(wp);
        const float4 f1 = *(const float4*)(wp + 4);
        const float4 g0 = *(const float4*)(wp + 32);
        const float4 g1 = *(const float4*)(wp + 36);
        const bf16x8 wa0 = pack8(f0, f1);
        const bf16x8 wa1 = pack8(g0, g1);
        __syncthreads();

        const bf16x8 bA0 = *(const bf16x8*)&At[l15*40 + lhi*8];
        const bf16x8 bA1 = *(const bf16x8*)&At[(16 + l15)*40 + lhi*8];
        #pragma unroll
        for (int mi = 0; mi < 5; ++mi) {
            const int m = wave + mi*4;
            const int r = m*16 + l15;
            const bf16x8 af = *(const bf16x8*)&xa[r*40 + lhi*8];
            const f32x4 d0 = mfma16(af, bA0, zero4);
            const f32x4 d1 = mfma16(af, bA1, zero4);
            const int t = m >> 2, c0 = (m & 3)*16 + lhi*4;
            uint2 p0;
            p0.x = (unsigned)f2bf(d0[0]) | ((unsigned)f2bf(d0[1]) << 16);
            p0.y = (unsigned)f2bf(d0[2]) | ((unsigned)f2bf(d0[3]) << 16);
            *(uint2*)&zt[(t*25 + l15)*72 + c0] = p0;
            if (l15 < 9) {
                uint2 p1;
                p1.x = (unsigned)f2bf(d1[0]) | ((unsigned)f2bf(d1[1]) << 16);
                p1.y = (unsigned)f2bf(d1[2]) | ((unsigned)f2bf(d1[3]) << 16);
                *(uint2*)&zt[(t*25 + 16 + l15)*72 + c0] = p1;
            }
        }
        __syncthreads();

        #pragma unroll
        for (int nt = 0; nt < 8; ++nt) {
            const int tw = nt*16 + l15;
            const bf16x8 b0 = *(const bf16x8*)&zt[tw*72 + lhi*8];
            const bf16x8 b1 = *(const bf16x8*)&zt[tw*72 + 32 + lhi*8];
            yacc[nt] = mfma16(wa0, b0, yacc[nt]);
            yacc[nt] = mfma16(wa1, b1, yacc[nt]);
        }
    }

    float bsum[4];
    #pragma unroll
    for (int rg = 0; rg < 4; ++rg) {
        const int o = obase + lhi*4 + rg;
        float s = 0.f;
        #pragma unroll
        for (int h = 0; h < H_; ++h) s += bd[h*64 + o];
        bsum[rg] = s;
    }
    float s1[4] = {0,0,0,0}, s2[4] = {0,0,0,0};
    #pragma unroll
    for (int nt = 0; nt < 8; ++nt) {
        const int tw = nt*16 + l15;
        if (tw < 125) {
            #pragma unroll
            for (int rg = 0; rg < 4; ++rg) {
                const float v = yacc[nt][rg] + bsum[rg];
                yacc[nt][rg] = v;
                s1[rg] += v;
                s2[rg] += v*v;
            }
        }
    }
    #pragma unroll
    for (int rg = 0; rg < 4; ++rg) {
        #pragma unroll
        for (int off = 1; off < 16; off <<= 1) {
            s1[rg] += __shfl_xor(s1[rg], off, 64);
            s2[rg] += __shfl_xor(s2[rg], off, 64);
        }
    }
    if (l15 == 0) {
        const int slot = (n*NCK + ck) & 31;
        #pragma unroll
        for (int rg = 0; rg < 4; ++rg) {
            const int o = obase + lhi*4 + rg;
            atomicAdd(&bnS[o*32 + slot], s1[rg]);
            atomicAdd(&bnS[2048 + o*32 + slot], s2[rg]);
        }
    }
    float* yo = y_out + n*CTV_ + ck*125;
    #pragma unroll
    for (int nt = 0; nt < 8; ++nt) {
        const int tw = nt*16 + l15;
        if (tw < 125) {
            #pragma unroll
            for (int rg = 0; rg < 4; ++rg) {
                const int o = obase + lhi*4 + rg;
                yo[o*TV_ + tw] = yacc[nt][rg];
            }
        }
    }
}

// ---------------- kernel 3r: fold 32-way-spread BN partials -> bn_acc[128] -----
__global__ void k3_reduce(const float* __restrict__ bnS, float* __restrict__ bn_acc)
{
    const int tid = threadIdx.x;
    if (tid < 128) {
        float s = 0.f;
        #pragma unroll
        for (int i = 0; i < 32; ++i) s += bnS[tid*32 + i];
        bn_acc[tid] = s;
    }
}

// ---------------- kernel 4: BN normalize + residual + relu ---------------------
__global__ __launch_bounds__(256) void k4_bn(
    float* yio, const float* __restrict__ x, const float* __restrict__ bn_acc,
    const float* __restrict__ gamma, const float* __restrict__ beta)
{
    const int idx = blockIdx.x*256 + threadIdx.x;
    const int c = (idx / 1875) & 63;
    const float invM = 1.0f / 240000.0f;
    const float mean = bn_acc[c] * invM;
    const float var  = bn_acc[64 + c] * invM - mean*mean;
    const float scale = gamma[c] * rsqrtf(var + 1e-5f);
    const float shift = beta[c] - mean*scale;
    const float4 y4 = reinterpret_cast<const float4*>(yio)[idx];
    const float4 x4 = reinterpret_cast<const float4*>(x)[idx];
    float4 r;
    r.x = fmaxf(0.f, fmaf(y4.x, scale, shift) + x4.x);
    r.y = fmaxf(0.f, fmaf(y4.y, scale, shift) + x4.y);
    r.z = fmaxf(0.f, fmaf(y4.z, scale, shift) + x4.z);
    r.w = fmaxf(0.f, fmaf(y4.w, scale, shift) + x4.w);
    reinterpret_cast<float4*>(yio)[idx] = r;
}

extern "C" void kernel_launch(void* const* d_in, const int* in_sizes, int n_in,
                              void* d_out, int out_size, void* d_ws, size_t ws_size,
                              hipStream_t stream) {
    const float* x     = (const float*)d_in[0];
    const float* DepM  = (const float*)d_in[1];
    const float* wa    = (const float*)d_in[2];
    const float* ba    = (const float*)d_in[3];
    const float* wb    = (const float*)d_in[4];
    const float* bb    = (const float*)d_in[5];
    const float* wd    = (const float*)d_in[6];
    const float* bd    = (const float*)d_in[7];
    const float* gamma = (const float*)d_in[8];
    const float* beta  = (const float*)d_in[9];
    float* out = (float*)d_out;

    float* A_ws   = (float*)d_ws;
    float* bnS    = (float*)d_ws + 160000;
    float* bn_acc = (float*)d_ws + 164096;
    float* s_part = out;   // gram partials use d_out as scratch before y overwrites

    k1_mfma<<<dim3(N_, NCH1), dim3(256), 0, stream>>>(x, wa, ba, wb, bb, s_part);
    k2_softmax<<<dim3(H_, N_), dim3(256), 0, stream>>>(s_part, DepM, A_ws);
    (void)hipMemsetAsync(bnS, 0, 4096*sizeof(float), stream);
    k3_mfma<<<dim3(N_, NCK), dim3(256), 0, stream>>>(x, A_ws, wd, bd, out, bnS);
    k3_reduce<<<dim3(1), dim3(128), 0, stream>>>(bnS, bn_acc);
    k4_bn<<<dim3(15000), dim3(256), 0, stream>>>(out, x, bn_acc, gamma, beta);
}